// Round 4
// baseline (227.573 us; speedup 1.0000x reference)
//
#include <hip/hip_runtime.h>
#include <math.h>

// Problem constants (B=16, C=3 -> 48 planes of 512x512)
#define H_IMG 512
#define W_IMG 512
#define R_OUT 45            // output rows per strip (R_OUT+10 = 55 = 5*11)
#define NWC   10            // wave-columns: ceil(512/54)
#define NRS   12            // row strips:  ceil(512/45)
#define WPB   4             // waves per block
#define NTHREADS 256

// Gaussian 11-tap, sigma=1.5, normalized (outer(w,w) == ref 2D window).
#define W0 0.00102838f
#define W1 0.00759873f
#define W2 0.03600075f
#define W3 0.10936070f
#define W4 0.21300556f
#define W5 0.26601172f

#define C1F (0.01f*0.01f)
#define C2F (0.03f*0.03f)

// One streamed input row. U is a compile-time step index (t_rel % 11);
// WARM=true only for the first 11-step block (slot warmup + first emit).
#define DO_STEP(U, WARM)                                                      \
  {                                                                           \
    const int t_rel  = tbase + (U);                                           \
    const int in_row = in_row0 + t_rel;                                       \
    const bool rowok = (unsigned)in_row < (unsigned)H_IMG;                    \
    float xv = 0.f, yv = 0.f;                                                 \
    if (rowok) { xv = px_row[0] * cmask; yv = py_row[0] * cmask; }            \
    px_row += W_IMG; py_row += W_IMG;                                         \
    if (rowok && t_rel >= 5 && t_rel < 5 + R_OUT) {                           \
      float d = (xv - yv) * emask;                                            \
      mse_acc = fmaf(d, d, mse_acc);                                          \
    }                                                                         \
    if (rowok) {                                                              \
      int xi = __float_as_int(xv), yi = __float_as_int(yv);                   \
      float xs[11], ys[11];                                                   \
      xs[5] = xv; ys[5] = yv;                                                 \
      _Pragma("unroll")                                                       \
      for (int i = 0; i < 10; ++i) {                                          \
        int s_ = (i < 5) ? i : (i + 1);                                       \
        xs[s_] = __int_as_float(__builtin_amdgcn_ds_bpermute(ad[i], xi));     \
        ys[s_] = __int_as_float(__builtin_amdgcn_ds_bpermute(ad[i], yi));     \
      }                                                                       \
      float hx=0.f, hy=0.f, hxx=0.f, hyy=0.f, hxy=0.f;                        \
      _Pragma("unroll")                                                       \
      for (int p = 0; p < 11; ++p) {                                          \
        float a = xs[p], b = ys[p], wv = cw11[p];                             \
        hx  = fmaf(wv, a,   hx);                                              \
        hy  = fmaf(wv, b,   hy);                                              \
        hxx = fmaf(wv, a*a, hxx);                                             \
        hyy = fmaf(wv, b*b, hyy);                                             \
        hxy = fmaf(wv, a*b, hxy);                                             \
      }                                                                       \
      _Pragma("unroll")                                                       \
      for (int j = 0; j < 11; ++j) {                                          \
        if (!(WARM) || j <= (U)) {                                            \
          float wv = cw11[((U) - j + 11) % 11];                               \
          a0[j] = fmaf(wv, hx,  a0[j]);                                       \
          a1[j] = fmaf(wv, hy,  a1[j]);                                       \
          a2[j] = fmaf(wv, hxx, a2[j]);                                       \
          a3[j] = fmaf(wv, hyy, a3[j]);                                       \
          a4[j] = fmaf(wv, hxy, a4[j]);                                       \
        }                                                                     \
      }                                                                       \
    }                                                                         \
    if (!(WARM) || (U) == 10) {                                               \
      const int je = ((U) + 1) % 11;                                          \
      const int orow = rs*R_OUT + t_rel - 10;                                 \
      if (orow < H_IMG) {                                                     \
        float mx = a0[je], my = a1[je];                                       \
        float sxx = a2[je] - mx*mx;                                           \
        float syy = a3[je] - my*my;                                           \
        float sxy = a4[je] - mx*my;                                           \
        float num = (2.f*mx*my + C1F) * (2.f*sxy + C2F);                      \
        float den = (mx*mx + my*my + C1F) * (sxx + syy + C2F);                \
        num = outlane ? num : 0.f;                                            \
        den = outlane ? den : 1.f;                                            \
        ssim_acc += __fdividef(num, den);                                     \
      }                                                                       \
      a0[je]=0.f; a1[je]=0.f; a2[je]=0.f; a3[je]=0.f; a4[je]=0.f;             \
    }                                                                         \
  }

__global__ __launch_bounds__(NTHREADS) void ssim_stream(
        const float* __restrict__ cover, const float* __restrict__ wmed,
        float* __restrict__ part, int nParts) {
    const float cw11[11] = {W0,W1,W2,W3,W4,W5,W4,W3,W2,W1,W0};

    const int tid  = threadIdx.x;
    const int lane = tid & 63;
    const int wid  = blockIdx.x * WPB + (tid >> 6);
    const int cw   = wid % NWC;
    const int tmp  = wid / NWC;
    const int rs   = tmp % NRS;
    const int pl   = tmp / NRS;

    const size_t pbase = (size_t)pl * (H_IMG*W_IMG);
    const float* xp = wmed + pbase;   // x = wmed, y = cover (as in reference)
    const float* yp = cover + pbase;

    // Column ownership: lane holds col cw*54-5+lane; lanes 5..58 emit outputs.
    const int col   = cw*54 - 5 + lane;
    const int ccol  = min(max(col, 0), W_IMG-1);
    const float cmask = (col >= 0 && col < W_IMG) ? 1.f : 0.f;
    const bool outlane = (lane >= 5 && lane <= 58 && col < W_IMG);
    const float emask  = outlane ? 1.f : 0.f;

    // bpermute byte-addresses for horizontal offsets d = -5..-1, +1..+5
    int ad[10];
#pragma unroll
    for (int i = 0; i < 10; ++i) {
        int d = (i < 5) ? (i - 5) : (i - 4);
        ad[i] = ((lane + d) & 63) << 2;
    }

    const int in_row0 = rs*R_OUT - 5;
    const float* px_row = xp + (ptrdiff_t)in_row0 * W_IMG + ccol;
    const float* py_row = yp + (ptrdiff_t)in_row0 * W_IMG + ccol;

    // 11 in-flight vertical accumulators per field
    float a0[11], a1[11], a2[11], a3[11], a4[11];
#pragma unroll
    for (int j = 0; j < 11; ++j) { a0[j]=0.f; a1[j]=0.f; a2[j]=0.f; a3[j]=0.f; a4[j]=0.f; }

    float ssim_acc = 0.f, mse_acc = 0.f;

    // Warmup block: t_rel = 0..10 (static conditions), first emit at t_rel=10
    int tbase = 0;
    DO_STEP(0,true)  DO_STEP(1,true)  DO_STEP(2,true)  DO_STEP(3,true)
    DO_STEP(4,true)  DO_STEP(5,true)  DO_STEP(6,true)  DO_STEP(7,true)
    DO_STEP(8,true)  DO_STEP(9,true)  DO_STEP(10,true)

    // Steady state: 4 blocks of 11 rows, one output row per step
#pragma clang loop unroll(disable)
    for (int tb = 1; tb < 5; ++tb) {
        tbase = 11*tb;
        DO_STEP(0,false)  DO_STEP(1,false)  DO_STEP(2,false)  DO_STEP(3,false)
        DO_STEP(4,false)  DO_STEP(5,false)  DO_STEP(6,false)  DO_STEP(7,false)
        DO_STEP(8,false)  DO_STEP(9,false)  DO_STEP(10,false)
    }

    // Per-wave reduction, one partial pair per wave
#pragma unroll
    for (int off = 32; off > 0; off >>= 1) {
        ssim_acc += __shfl_down(ssim_acc, off);
        mse_acc  += __shfl_down(mse_acc, off);
    }
    if (lane == 0) {
        part[wid] = ssim_acc;
        part[nParts + wid] = mse_acc;
    }
}

// 1024-thread finalize: vectorized partial reduce (double), fast-log BCE,
// curriculum weights.
#define FT 1024
__global__ __launch_bounds__(FT) void finalize_k(
        const float* __restrict__ part, int nParts,
        const float* __restrict__ wm_orig, const float* __restrict__ wm_ext,
        int nWm, const int* __restrict__ epoch_p,
        float* __restrict__ out, double inv_npix, double inv_nwm) {
    __shared__ double red[48];
    int tid = threadIdx.x;
    double s_ssim = 0.0, s_mse = 0.0, s_wl = 0.0;
    const float4* s4 = (const float4*)part;
    const float4* m4 = (const float4*)(part + nParts);
    int n4 = nParts >> 2;
    for (int i = tid; i < n4; i += FT) {
        float4 v = s4[i];
        s_ssim += (double)((v.x + v.y) + (v.z + v.w));
        float4 u = m4[i];
        s_mse  += (double)((u.x + u.y) + (u.z + u.w));
    }
    const float4* p4 = (const float4*)wm_orig;
    const float4* q4 = (const float4*)wm_ext;
    int w4 = nWm >> 2;
    for (int i = tid; i < w4; i += FT) {
        float4 p = p4[i], q = q4[i];
        float a;
        a  = -(p.x*__logf(q.x) + (1.f-p.x)*__logf(1.f-q.x));
        a += -(p.y*__logf(q.y) + (1.f-p.y)*__logf(1.f-q.y));
        a += -(p.z*__logf(q.z) + (1.f-p.z)*__logf(1.f-q.z));
        a += -(p.w*__logf(q.w) + (1.f-p.w)*__logf(1.f-q.w));
        s_wl += (double)a;
    }
#pragma unroll
    for (int off = 32; off > 0; off >>= 1) {
        s_ssim += __shfl_down(s_ssim, off);
        s_mse  += __shfl_down(s_mse, off);
        s_wl   += __shfl_down(s_wl, off);
    }
    int wid = tid >> 6, lane = tid & 63;
    if (lane == 0) { red[wid] = s_ssim; red[16+wid] = s_mse; red[32+wid] = s_wl; }
    __syncthreads();
    if (tid == 0) {
        double ssim_sum = 0.0, mse_sum = 0.0, wl_sum = 0.0;
        for (int i = 0; i < 16; ++i) {
            ssim_sum += red[i]; mse_sum += red[16+i]; wl_sum += red[32+i];
        }
        float sv = (float)(ssim_sum * inv_npix);
        float ml = (float)(mse_sum  * inv_npix);
        float wl = (float)(wl_sum   * inv_nwm);
        int e = *epoch_p;
        float w_img, w_ssim;
        if (e <= 12) {
            w_img = 0.05f; w_ssim = 0.05f;
        } else {
            float progress = fminf(1.0f, (float)(e - 12) / 10.0f);
            w_img  = 0.05f + (0.5f - 0.05f)*progress;
            w_ssim = 0.05f + (0.8f - 0.05f)*progress;
        }
        float sl = 1.0f - sv;
        float total = w_img*ml + w_ssim*sl + 3.0f*wl;
        out[0] = total;
        out[1] = ml;
        out[2] = sv;
        out[3] = wl;
    }
}

extern "C" void kernel_launch(void* const* d_in, const int* in_sizes, int n_in,
                              void* d_out, int out_size, void* d_ws, size_t ws_size,
                              hipStream_t stream) {
    const float* cover   = (const float*)d_in[0];
    const float* wmed    = (const float*)d_in[1];
    const float* wm_orig = (const float*)d_in[2];
    const float* wm_ext  = (const float*)d_in[3];
    const int*   epoch   = (const int*)d_in[4];
    float* out = (float*)d_out;

    int npix   = in_sizes[0];                 // 12,582,912
    int planes = npix / (H_IMG * W_IMG);      // 48
    int nWm    = in_sizes[2];                 // 16,384

    int nWaves  = NWC * NRS * planes;         // 5760 wave tasks
    int nBlocks = nWaves / WPB;               // 1440 blocks of 4 waves
    int nParts  = nWaves;
    float* part = (float*)d_ws;               // 2 * nParts floats (46 KB)

    ssim_stream<<<nBlocks, NTHREADS, 0, stream>>>(cover, wmed, part, nParts);
    finalize_k<<<1, FT, 0, stream>>>(part, nParts, wm_orig, wm_ext, nWm,
                                     epoch, out,
                                     1.0 / (double)npix, 1.0 / (double)nWm);
}

// Round 5
// 198.527 us; speedup vs baseline: 1.1463x; 1.1463x over previous
//
#include <hip/hip_runtime.h>
#include <math.h>

// Problem constants (B=16, C=3 -> 48 planes of 512x512)
#define H_IMG 512
#define W_IMG 512
#define TH 32
#define TW 32
#define HALO 5
#define WS11 11
#define SH (TH + 2*HALO)   // 42 rows incl. halo
#define NTHREADS 256
#define TPB 4              // tiles per block (x-adjacent)

// rbuf layout: [row 0..41][field 0..4][col 0..31], field stride 33, row 165.
// Banks: addr%32 = (5r + f + c)%32 -> stage-B lanes (c=0..31) are a
// permutation (conflict-free); stage-A writes are 2-way (free). (R2-verified:
// SQ_LDS_BANK_CONFLICT == 0.)
#define RWF 33
#define RWR (5*RWF)        // 165
#define RBUF_N (SH*RWR)    // 6930 floats = 27720 B

// Gaussian 11-tap, sigma=1.5, normalized (outer(w,w) == ref 2D window).
#define W0 0.00102838f
#define W1 0.00759873f
#define W2 0.03600075f
#define W3 0.10936070f
#define W4 0.21300556f
#define W5 0.26601172f
__device__ __constant__ float c_w[WS11] = {W0,W1,W2,W3,W4,W5,W4,W3,W2,W1,W0};

__global__ __launch_bounds__(NTHREADS, 5) void ssim_mse_tile(
        const float* __restrict__ cover, const float* __restrict__ wmed,
        float* __restrict__ part, int nParts) {
    __shared__ __align__(16) float rbuf[RBUF_N];   // 27720 B
    __shared__ float red[8];

    const int tid = threadIdx.x;
    float ssim_acc = 0.f, mse_acc = 0.f;

    for (int it = 0; it < TPB; ++it) {
        const int tile = blockIdx.x * TPB + it;
        const int bx = tile & 15;
        const int by = (tile >> 4) & 15;
        const int pl = tile >> 8;
        const size_t pbase = (size_t)pl * (H_IMG*W_IMG);
        const float* xp = wmed + pbase;   // x = wmed, y = cover
        const float* yp = cover + pbase;
        const int ty0 = by*TH - HALO;
        const int tx0 = bx*TW - HALO;
        const bool xin = (bx != 0) && (bx != 15);   // fast-path columns

        // ---- Stage A: horizontal 11-tap conv of 5 fields, from global ----
        // 42 rows x 8 col-groups = 336 tasks; 4 outputs from 14-wide window.
        for (int t = tid; t < SH*8; t += NTHREADS) {
            const int r = t >> 3, c0 = (t & 7) << 2;
            const int gy = ty0 + r;
            const bool rok = (unsigned)gy < (unsigned)H_IMG;
            float xv[14], yv[14];
            if (rok && xin) {
                // ga = tx0+c0-3 == bx*32+c0-8 : 16B-aligned, in [24, 484]
                const int ga = tx0 + c0 - 3;
                const float* rx = xp + (size_t)gy*W_IMG + ga;
                const float* ry = yp + (size_t)gy*W_IMG + ga;
                float4 XA = *(const float4*)(rx);
                float4 XB = *(const float4*)(rx + 4);
                float4 XC = *(const float4*)(rx + 8);
                float4 XD = *(const float4*)(rx + 12);
                float  XE = rx[16];
                float4 YA = *(const float4*)(ry);
                float4 YB = *(const float4*)(ry + 4);
                float4 YC = *(const float4*)(ry + 8);
                float4 YD = *(const float4*)(ry + 12);
                float  YE = ry[16];
                xv[0]=XA.w;  xv[1]=XB.x;  xv[2]=XB.y;  xv[3]=XB.z;  xv[4]=XB.w;
                xv[5]=XC.x;  xv[6]=XC.y;  xv[7]=XC.z;  xv[8]=XC.w;  xv[9]=XD.x;
                xv[10]=XD.y; xv[11]=XD.z; xv[12]=XD.w; xv[13]=XE;
                yv[0]=YA.w;  yv[1]=YB.x;  yv[2]=YB.y;  yv[3]=YB.z;  yv[4]=YB.w;
                yv[5]=YC.x;  yv[6]=YC.y;  yv[7]=YC.z;  yv[8]=YC.w;  yv[9]=YD.x;
                yv[10]=YD.y; yv[11]=YD.z; yv[12]=YD.w; yv[13]=YE;
            } else if (rok) {
                const int gc = tx0 + c0;
                const float* prx = xp + (size_t)gy*W_IMG + gc;
                const float* pry = yp + (size_t)gy*W_IMG + gc;
#pragma unroll
                for (int j = 0; j < 14; ++j) {
                    bool ok = (unsigned)(gc + j) < (unsigned)W_IMG;
                    xv[j] = ok ? prx[j] : 0.f;
                    yv[j] = ok ? pry[j] : 0.f;
                }
            } else {
#pragma unroll
                for (int j = 0; j < 14; ++j) { xv[j] = 0.f; yv[j] = 0.f; }
            }

            // fused MSE: interior pixels are window j=5..8, rows 5..36
            if (rok && r >= HALO && r < HALO+TH) {
#pragma unroll
                for (int j = 5; j < 9; ++j) {
                    float d = xv[j] - yv[j];
                    mse_acc = fmaf(d, d, mse_acc);
                }
            }

            float a0[4]={0,0,0,0}, a1[4]={0,0,0,0}, a2[4]={0,0,0,0};
            float a3[4]={0,0,0,0}, a4[4]={0,0,0,0};
#pragma unroll
            for (int j = 0; j < 14; ++j) {
                float px = xv[j], py = yv[j];
                float pxx = px*px, pyy = py*py, pxy = px*py;
#pragma unroll
                for (int k = 0; k < 4; ++k) {
                    int tap = j - k;                  // compile-time resolved
                    if (tap >= 0 && tap < WS11) {
                        float wv = c_w[tap];
                        a0[k] = fmaf(wv, px,  a0[k]);
                        a1[k] = fmaf(wv, py,  a1[k]);
                        a2[k] = fmaf(wv, pxx, a2[k]);
                        a3[k] = fmaf(wv, pyy, a3[k]);
                        a4[k] = fmaf(wv, pxy, a4[k]);
                    }
                }
            }
            float* wb = &rbuf[r*RWR + c0];
#pragma unroll
            for (int k = 0; k < 4; ++k) {
                wb[0*RWF + k] = a0[k];
                wb[1*RWF + k] = a1[k];
                wb[2*RWF + k] = a2[k];
                wb[3*RWF + k] = a3[k];
                wb[4*RWF + k] = a4[k];
            }
        }
        __syncthreads();

        // ---- Stage B: vertical 11-tap conv + SSIM; 4 outputs per thread ----
        {
            const float C1 = 0.01f*0.01f, C2 = 0.03f*0.03f;
            const int c  = tid & 31;
            const int r0 = (tid >> 5) << 2;
            float m0[4]={0,0,0,0}, m1[4]={0,0,0,0}, e2[4]={0,0,0,0};
            float e3[4]={0,0,0,0}, e4[4]={0,0,0,0};
#pragma unroll
            for (int i = 0; i < 14; ++i) {
                const float* rb = &rbuf[(r0 + i)*RWR + c];
                float v0 = rb[0*RWF], v1 = rb[1*RWF], v2 = rb[2*RWF];
                float v3 = rb[3*RWF], v4 = rb[4*RWF];
#pragma unroll
                for (int k = 0; k < 4; ++k) {
                    int tap = i - k;
                    if (tap >= 0 && tap < WS11) {
                        float wv = c_w[tap];
                        m0[k] = fmaf(wv, v0, m0[k]);
                        m1[k] = fmaf(wv, v1, m1[k]);
                        e2[k] = fmaf(wv, v2, e2[k]);
                        e3[k] = fmaf(wv, v3, e3[k]);
                        e4[k] = fmaf(wv, v4, e4[k]);
                    }
                }
            }
#pragma unroll
            for (int k = 0; k < 4; ++k) {
                float mx = m0[k], my = m1[k];
                float sxx = e2[k] - mx*mx;
                float syy = e3[k] - my*my;
                float sxy = e4[k] - mx*my;
                float num = (2.f*mx*my + C1) * (2.f*sxy + C2);
                float den = (mx*mx + my*my + C1) * (sxx + syy + C2);
                ssim_acc += __fdividef(num, den);
            }
        }
        __syncthreads();   // rbuf reused by next tile
    }

    // ---- Block reduce (4 waves of 64) ----
#pragma unroll
    for (int off = 32; off > 0; off >>= 1) {
        ssim_acc += __shfl_down(ssim_acc, off);
        mse_acc  += __shfl_down(mse_acc, off);
    }
    int wid = tid >> 6, lane = tid & 63;
    if (lane == 0) { red[wid] = ssim_acc; red[4+wid] = mse_acc; }
    __syncthreads();
    if (tid == 0) {
        float s = red[0]+red[1]+red[2]+red[3];
        float m = red[4]+red[5]+red[6]+red[7];
        part[blockIdx.x] = s;
        part[nParts + blockIdx.x] = m;
    }
}

// 1024-thread finalize: vectorized partial reduce (double), fast-log BCE,
// curriculum weights.
#define FT 1024
__global__ __launch_bounds__(FT) void finalize_k(
        const float* __restrict__ part, int nParts,
        const float* __restrict__ wm_orig, const float* __restrict__ wm_ext,
        int nWm, const int* __restrict__ epoch_p,
        float* __restrict__ out, double inv_npix, double inv_nwm) {
    __shared__ double red[48];
    int tid = threadIdx.x;
    double s_ssim = 0.0, s_mse = 0.0, s_wl = 0.0;
    const float4* s4 = (const float4*)part;
    const float4* m4 = (const float4*)(part + nParts);
    int n4 = nParts >> 2;
    for (int i = tid; i < n4; i += FT) {
        float4 v = s4[i];
        s_ssim += (double)((v.x + v.y) + (v.z + v.w));
        float4 u = m4[i];
        s_mse  += (double)((u.x + u.y) + (u.z + u.w));
    }
    const float4* p4 = (const float4*)wm_orig;
    const float4* q4 = (const float4*)wm_ext;
    int w4 = nWm >> 2;
    for (int i = tid; i < w4; i += FT) {
        float4 p = p4[i], q = q4[i];
        float a;
        a  = -(p.x*__logf(q.x) + (1.f-p.x)*__logf(1.f-q.x));
        a += -(p.y*__logf(q.y) + (1.f-p.y)*__logf(1.f-q.y));
        a += -(p.z*__logf(q.z) + (1.f-p.z)*__logf(1.f-q.z));
        a += -(p.w*__logf(q.w) + (1.f-p.w)*__logf(1.f-q.w));
        s_wl += (double)a;
    }
#pragma unroll
    for (int off = 32; off > 0; off >>= 1) {
        s_ssim += __shfl_down(s_ssim, off);
        s_mse  += __shfl_down(s_mse, off);
        s_wl   += __shfl_down(s_wl, off);
    }
    int wid = tid >> 6, lane = tid & 63;
    if (lane == 0) { red[wid] = s_ssim; red[16+wid] = s_mse; red[32+wid] = s_wl; }
    __syncthreads();
    if (tid == 0) {
        double ssim_sum = 0.0, mse_sum = 0.0, wl_sum = 0.0;
        for (int i = 0; i < 16; ++i) {
            ssim_sum += red[i]; mse_sum += red[16+i]; wl_sum += red[32+i];
        }
        float sv = (float)(ssim_sum * inv_npix);
        float ml = (float)(mse_sum  * inv_npix);
        float wl = (float)(wl_sum   * inv_nwm);
        int e = *epoch_p;
        float w_img, w_ssim;
        if (e <= 12) {
            w_img = 0.05f; w_ssim = 0.05f;
        } else {
            float progress = fminf(1.0f, (float)(e - 12) / 10.0f);
            w_img  = 0.05f + (0.5f - 0.05f)*progress;
            w_ssim = 0.05f + (0.8f - 0.05f)*progress;
        }
        float sl = 1.0f - sv;
        float total = w_img*ml + w_ssim*sl + 3.0f*wl;
        out[0] = total;
        out[1] = ml;
        out[2] = sv;
        out[3] = wl;
    }
}

extern "C" void kernel_launch(void* const* d_in, const int* in_sizes, int n_in,
                              void* d_out, int out_size, void* d_ws, size_t ws_size,
                              hipStream_t stream) {
    const float* cover   = (const float*)d_in[0];
    const float* wmed    = (const float*)d_in[1];
    const float* wm_orig = (const float*)d_in[2];
    const float* wm_ext  = (const float*)d_in[3];
    const int*   epoch   = (const int*)d_in[4];
    float* out = (float*)d_out;

    int npix   = in_sizes[0];                 // 12,582,912
    int planes = npix / (H_IMG * W_IMG);      // 48
    int nWm    = in_sizes[2];                 // 16,384

    int nTiles  = 16 * 16 * planes;           // 12288
    int nBlocks = nTiles / TPB;               // 3072 blocks, 4 x-adjacent tiles
    int nParts  = nBlocks;
    float* part = (float*)d_ws;               // 2 * nParts floats (24 KB)

    ssim_mse_tile<<<nBlocks, NTHREADS, 0, stream>>>(cover, wmed, part, nParts);
    finalize_k<<<1, FT, 0, stream>>>(part, nParts, wm_orig, wm_ext, nWm,
                                     epoch, out,
                                     1.0 / (double)npix, 1.0 / (double)nWm);
}

// Round 6
// 198.435 us; speedup vs baseline: 1.1468x; 1.0005x over previous
//
#include <hip/hip_runtime.h>
#include <math.h>

// Problem constants (B=16, C=3 -> 48 planes of 512x512)
#define H_IMG 512
#define W_IMG 512
#define TH 32
#define TW 32
#define HALO 5
#define WS11 11
#define SH (TH + 2*HALO)   // 42 rows incl. halo
#define NTHREADS 256
#define TPB 4              // tiles per block (x-adjacent)

// rbuf layout: [field 0..4][row 0..41][col 0..31], row stride 36 floats
// (144 B, 16B-aligned -> b128 ok). Stage-A b128 writes: bank-quad =
// (r + c/4) mod 8 -> 8 lanes/quad, balanced. Stage-B b32 reads: lanes 0..31
// consecutive cols (perm), lanes 32..63 offset 8*36*4B = 0 mod 32 banks ->
// 2-way aliasing = free (m136).
#define RS 36
#define RBUF_N (5*SH*RS)   // 7560 floats = 30240 B

// Gaussian 11-tap, sigma=1.5, normalized (outer(w,w) == ref 2D window).
#define W0 0.00102838f
#define W1 0.00759873f
#define W2 0.03600075f
#define W3 0.10936070f
#define W4 0.21300556f
#define W5 0.26601172f
__device__ __constant__ float c_w[WS11] = {W0,W1,W2,W3,W4,W5,W4,W3,W2,W1,W0};

__global__ __launch_bounds__(NTHREADS, 4) void ssim_mse_tile(
        const float* __restrict__ cover, const float* __restrict__ wmed,
        float* __restrict__ part, int nParts) {
    __shared__ __align__(16) float rbuf[RBUF_N];   // 30240 B
    __shared__ float red[8];

    const int tid = threadIdx.x;
    float ssim_acc = 0.f, mse_acc = 0.f;

    for (int it = 0; it < TPB; ++it) {
        const int tile = blockIdx.x * TPB + it;
        const int bx = tile & 15;
        const int by = (tile >> 4) & 15;
        const int pl = tile >> 8;
        const size_t pbase = (size_t)pl * (H_IMG*W_IMG);
        const float* xp = wmed + pbase;   // x = wmed, y = cover
        const float* yp = cover + pbase;
        const int ty0 = by*TH - HALO;
        const int tx0 = bx*TW - HALO;
        const bool xin = (bx != 0) && (bx != 15);   // fast-path columns

        // ---- Stage A: horizontal 11-tap conv of 5 fields, from global ----
        // 42 rows x 8 col-groups = 336 tasks; 4 outputs from 14-wide window.
        for (int t = tid; t < SH*8; t += NTHREADS) {
            const int r = t >> 3, c0 = (t & 7) << 2;
            const int gy = ty0 + r;
            const bool rok = (unsigned)gy < (unsigned)H_IMG;
            float xv[14], yv[14];
            if (rok && xin) {
                // ga = tx0+c0-3 == bx*32+c0-8 : 16B-aligned, in [24, 484]
                const int ga = tx0 + c0 - 3;
                const float* rx = xp + (size_t)gy*W_IMG + ga;
                const float* ry = yp + (size_t)gy*W_IMG + ga;
                float4 XA = *(const float4*)(rx);
                float4 XB = *(const float4*)(rx + 4);
                float4 XC = *(const float4*)(rx + 8);
                float4 XD = *(const float4*)(rx + 12);
                float  XE = rx[16];
                float4 YA = *(const float4*)(ry);
                float4 YB = *(const float4*)(ry + 4);
                float4 YC = *(const float4*)(ry + 8);
                float4 YD = *(const float4*)(ry + 12);
                float  YE = ry[16];
                xv[0]=XA.w;  xv[1]=XB.x;  xv[2]=XB.y;  xv[3]=XB.z;  xv[4]=XB.w;
                xv[5]=XC.x;  xv[6]=XC.y;  xv[7]=XC.z;  xv[8]=XC.w;  xv[9]=XD.x;
                xv[10]=XD.y; xv[11]=XD.z; xv[12]=XD.w; xv[13]=XE;
                yv[0]=YA.w;  yv[1]=YB.x;  yv[2]=YB.y;  yv[3]=YB.z;  yv[4]=YB.w;
                yv[5]=YC.x;  yv[6]=YC.y;  yv[7]=YC.z;  yv[8]=YC.w;  yv[9]=YD.x;
                yv[10]=YD.y; yv[11]=YD.z; yv[12]=YD.w; yv[13]=YE;
            } else if (rok) {
                const int gc = tx0 + c0;
                const float* prx = xp + (size_t)gy*W_IMG + gc;
                const float* pry = yp + (size_t)gy*W_IMG + gc;
#pragma unroll
                for (int j = 0; j < 14; ++j) {
                    bool ok = (unsigned)(gc + j) < (unsigned)W_IMG;
                    xv[j] = ok ? prx[j] : 0.f;
                    yv[j] = ok ? pry[j] : 0.f;
                }
            } else {
#pragma unroll
                for (int j = 0; j < 14; ++j) { xv[j] = 0.f; yv[j] = 0.f; }
            }

            // fused MSE: interior pixels are window j=5..8, rows 5..36
            if (rok && r >= HALO && r < HALO+TH) {
#pragma unroll
                for (int j = 5; j < 9; ++j) {
                    float d = xv[j] - yv[j];
                    mse_acc = fmaf(d, d, mse_acc);
                }
            }

            float a0[4]={0,0,0,0}, a1[4]={0,0,0,0}, a2[4]={0,0,0,0};
            float a3[4]={0,0,0,0}, a4[4]={0,0,0,0};
#pragma unroll
            for (int j = 0; j < 14; ++j) {
                float px = xv[j], py = yv[j];
                float pxx = px*px, pyy = py*py, pxy = px*py;
#pragma unroll
                for (int k = 0; k < 4; ++k) {
                    int tap = j - k;                  // compile-time resolved
                    if (tap >= 0 && tap < WS11) {
                        float wv = c_w[tap];
                        a0[k] = fmaf(wv, px,  a0[k]);
                        a1[k] = fmaf(wv, py,  a1[k]);
                        a2[k] = fmaf(wv, pxx, a2[k]);
                        a3[k] = fmaf(wv, pyy, a3[k]);
                        a4[k] = fmaf(wv, pxy, a4[k]);
                    }
                }
            }
            float* wb = &rbuf[r*RS + c0];
            *(float4*)(wb + 0*SH*RS) = make_float4(a0[0],a0[1],a0[2],a0[3]);
            *(float4*)(wb + 1*SH*RS) = make_float4(a1[0],a1[1],a1[2],a1[3]);
            *(float4*)(wb + 2*SH*RS) = make_float4(a2[0],a2[1],a2[2],a2[3]);
            *(float4*)(wb + 3*SH*RS) = make_float4(a3[0],a3[1],a3[2],a3[3]);
            *(float4*)(wb + 4*SH*RS) = make_float4(a4[0],a4[1],a4[2],a4[3]);
        }
        __syncthreads();

        // ---- Stage B: vertical 11-tap conv + SSIM; 8 rows per thread,
        //      128 active threads; alternate wave-pairs across tiles so
        //      the SIMD load stays balanced over the 4-tile loop. ----
        if (((tid >> 7) & 1) == (it & 1)) {
            const float C1 = 0.01f*0.01f, C2 = 0.03f*0.03f;
            const int s  = tid & 127;
            const int c  = s & 31;
            const int r0 = (s >> 5) << 3;    // 0, 8, 16, 24
            float acc[5][8];
#pragma unroll
            for (int f = 0; f < 5; ++f)
#pragma unroll
                for (int k = 0; k < 8; ++k) acc[f][k] = 0.f;
#pragma unroll
            for (int f = 0; f < 5; ++f) {
                const float* rb = &rbuf[f*SH*RS + r0*RS + c];
#pragma unroll
                for (int i = 0; i < 18; ++i) {
                    float v = rb[i*RS];
#pragma unroll
                    for (int k = 0; k < 8; ++k) {
                        int tap = i - k;
                        if (tap >= 0 && tap < WS11)
                            acc[f][k] = fmaf(c_w[tap], v, acc[f][k]);
                    }
                }
            }
#pragma unroll
            for (int k = 0; k < 8; ++k) {
                float mx = acc[0][k], my = acc[1][k];
                float sxx = acc[2][k] - mx*mx;
                float syy = acc[3][k] - my*my;
                float sxy = acc[4][k] - mx*my;
                float num = (2.f*mx*my + C1) * (2.f*sxy + C2);
                float den = (mx*mx + my*my + C1) * (sxx + syy + C2);
                ssim_acc += __fdividef(num, den);
            }
        }
        __syncthreads();   // rbuf reused by next tile
    }

    // ---- Block reduce (4 waves of 64) ----
#pragma unroll
    for (int off = 32; off > 0; off >>= 1) {
        ssim_acc += __shfl_down(ssim_acc, off);
        mse_acc  += __shfl_down(mse_acc, off);
    }
    int wid = tid >> 6, lane = tid & 63;
    if (lane == 0) { red[wid] = ssim_acc; red[4+wid] = mse_acc; }
    __syncthreads();
    if (tid == 0) {
        float s = red[0]+red[1]+red[2]+red[3];
        float m = red[4]+red[5]+red[6]+red[7];
        part[blockIdx.x] = s;
        part[nParts + blockIdx.x] = m;
    }
}

// 1024-thread finalize: vectorized partial reduce (double), fast-log BCE,
// curriculum weights.
#define FT 1024
__global__ __launch_bounds__(FT) void finalize_k(
        const float* __restrict__ part, int nParts,
        const float* __restrict__ wm_orig, const float* __restrict__ wm_ext,
        int nWm, const int* __restrict__ epoch_p,
        float* __restrict__ out, double inv_npix, double inv_nwm) {
    __shared__ double red[48];
    int tid = threadIdx.x;
    double s_ssim = 0.0, s_mse = 0.0, s_wl = 0.0;
    const float4* s4 = (const float4*)part;
    const float4* m4 = (const float4*)(part + nParts);
    int n4 = nParts >> 2;
    for (int i = tid; i < n4; i += FT) {
        float4 v = s4[i];
        s_ssim += (double)((v.x + v.y) + (v.z + v.w));
        float4 u = m4[i];
        s_mse  += (double)((u.x + u.y) + (u.z + u.w));
    }
    const float4* p4 = (const float4*)wm_orig;
    const float4* q4 = (const float4*)wm_ext;
    int w4 = nWm >> 2;
    for (int i = tid; i < w4; i += FT) {
        float4 p = p4[i], q = q4[i];
        float a;
        a  = -(p.x*__logf(q.x) + (1.f-p.x)*__logf(1.f-q.x));
        a += -(p.y*__logf(q.y) + (1.f-p.y)*__logf(1.f-q.y));
        a += -(p.z*__logf(q.z) + (1.f-p.z)*__logf(1.f-q.z));
        a += -(p.w*__logf(q.w) + (1.f-p.w)*__logf(1.f-q.w));
        s_wl += (double)a;
    }
#pragma unroll
    for (int off = 32; off > 0; off >>= 1) {
        s_ssim += __shfl_down(s_ssim, off);
        s_mse  += __shfl_down(s_mse, off);
        s_wl   += __shfl_down(s_wl, off);
    }
    int wid = tid >> 6, lane = tid & 63;
    if (lane == 0) { red[wid] = s_ssim; red[16+wid] = s_mse; red[32+wid] = s_wl; }
    __syncthreads();
    if (tid == 0) {
        double ssim_sum = 0.0, mse_sum = 0.0, wl_sum = 0.0;
        for (int i = 0; i < 16; ++i) {
            ssim_sum += red[i]; mse_sum += red[16+i]; wl_sum += red[32+i];
        }
        float sv = (float)(ssim_sum * inv_npix);
        float ml = (float)(mse_sum  * inv_npix);
        float wl = (float)(wl_sum   * inv_nwm);
        int e = *epoch_p;
        float w_img, w_ssim;
        if (e <= 12) {
            w_img = 0.05f; w_ssim = 0.05f;
        } else {
            float progress = fminf(1.0f, (float)(e - 12) / 10.0f);
            w_img  = 0.05f + (0.5f - 0.05f)*progress;
            w_ssim = 0.05f + (0.8f - 0.05f)*progress;
        }
        float sl = 1.0f - sv;
        float total = w_img*ml + w_ssim*sl + 3.0f*wl;
        out[0] = total;
        out[1] = ml;
        out[2] = sv;
        out[3] = wl;
    }
}

extern "C" void kernel_launch(void* const* d_in, const int* in_sizes, int n_in,
                              void* d_out, int out_size, void* d_ws, size_t ws_size,
                              hipStream_t stream) {
    const float* cover   = (const float*)d_in[0];
    const float* wmed    = (const float*)d_in[1];
    const float* wm_orig = (const float*)d_in[2];
    const float* wm_ext  = (const float*)d_in[3];
    const int*   epoch   = (const int*)d_in[4];
    float* out = (float*)d_out;

    int npix   = in_sizes[0];                 // 12,582,912
    int planes = npix / (H_IMG * W_IMG);      // 48
    int nWm    = in_sizes[2];                 // 16,384

    int nTiles  = 16 * 16 * planes;           // 12288
    int nBlocks = nTiles / TPB;               // 3072 blocks, 4 x-adjacent tiles
    int nParts  = nBlocks;
    float* part = (float*)d_ws;               // 2 * nParts floats (24 KB)

    ssim_mse_tile<<<nBlocks, NTHREADS, 0, stream>>>(cover, wmed, part, nParts);
    finalize_k<<<1, FT, 0, stream>>>(part, nParts, wm_orig, wm_ext, nWm,
                                     epoch, out,
                                     1.0 / (double)npix, 1.0 / (double)nWm);
}

// Round 7
// 181.762 us; speedup vs baseline: 1.2520x; 1.0917x over previous
//
#include <hip/hip_runtime.h>
#include <math.h>

// Problem constants (B=16, C=3 -> 48 planes of 512x512)
#define H_IMG 512
#define W_IMG 512
#define TH 32
#define TW 32
#define HALO 5
#define WS11 11
#define SH (TH + 2*HALO)   // 42 rows incl. halo
#define NTHREADS 256
#define TPB 4              // tiles per block (x-adjacent)

// rbuf layout: [field 0..4][row 0..41][col 0..31], row stride 36 floats.
#define RS 36
#define RBUF_N (5*SH*RS)   // 7560 floats = 30240 B

typedef float f2 __attribute__((ext_vector_type(2)));

// Gaussian 11-tap, sigma=1.5, normalized; tap accessor folds to a literal
// after full unroll (out-of-range -> 0 so packed lanes can run harmlessly).
__host__ __device__ constexpr float WT(int t) {
    return (t==0||t==10) ? 0.00102838f :
           (t==1||t==9)  ? 0.00759873f :
           (t==2||t==8)  ? 0.03600075f :
           (t==3||t==7)  ? 0.10936070f :
           (t==4||t==6)  ? 0.21300556f :
           (t==5)        ? 0.26601172f : 0.0f;
}

static __device__ __forceinline__ f2 splat2(float v) { f2 r = {v, v}; return r; }

__global__ __launch_bounds__(NTHREADS, 4) void ssim_mse_tile(
        const float* __restrict__ cover, const float* __restrict__ wmed,
        float* __restrict__ part, int nParts) {
    __shared__ __align__(16) float rbuf[RBUF_N];   // 30240 B
    __shared__ float red[8];

    const int tid = threadIdx.x;
    float ssim_acc = 0.f, mse_acc = 0.f;

    for (int it = 0; it < TPB; ++it) {
        const int tile = blockIdx.x * TPB + it;
        const int bx = tile & 15;
        const int by = (tile >> 4) & 15;
        const int pl = tile >> 8;
        const size_t pbase = (size_t)pl * (H_IMG*W_IMG);
        const float* xp = wmed + pbase;   // x = wmed, y = cover
        const float* yp = cover + pbase;
        const int ty0 = by*TH - HALO;
        const int tx0 = bx*TW - HALO;
        const bool xin = (bx != 0) && (bx != 15);   // fast-path columns

        // ---- Stage A: horizontal 11-tap conv of 5 fields, from global ----
        // 42 rows x 8 col-groups = 336 tasks; 4 outputs from 14-wide window.
        for (int t = tid; t < SH*8; t += NTHREADS) {
            const int r = t >> 3, c0 = (t & 7) << 2;
            const int gy = ty0 + r;
            const bool rok = (unsigned)gy < (unsigned)H_IMG;
            float xv[14], yv[14];
            if (rok && xin) {
                // ga = tx0+c0-3 == bx*32+c0-8 : 16B-aligned, in [24, 484]
                const int ga = tx0 + c0 - 3;
                const float* rx = xp + (size_t)gy*W_IMG + ga;
                const float* ry = yp + (size_t)gy*W_IMG + ga;
                float4 XA = *(const float4*)(rx);
                float4 XB = *(const float4*)(rx + 4);
                float4 XC = *(const float4*)(rx + 8);
                float4 XD = *(const float4*)(rx + 12);
                float  XE = rx[16];
                float4 YA = *(const float4*)(ry);
                float4 YB = *(const float4*)(ry + 4);
                float4 YC = *(const float4*)(ry + 8);
                float4 YD = *(const float4*)(ry + 12);
                float  YE = ry[16];
                xv[0]=XA.w;  xv[1]=XB.x;  xv[2]=XB.y;  xv[3]=XB.z;  xv[4]=XB.w;
                xv[5]=XC.x;  xv[6]=XC.y;  xv[7]=XC.z;  xv[8]=XC.w;  xv[9]=XD.x;
                xv[10]=XD.y; xv[11]=XD.z; xv[12]=XD.w; xv[13]=XE;
                yv[0]=YA.w;  yv[1]=YB.x;  yv[2]=YB.y;  yv[3]=YB.z;  yv[4]=YB.w;
                yv[5]=YC.x;  yv[6]=YC.y;  yv[7]=YC.z;  yv[8]=YC.w;  yv[9]=YD.x;
                yv[10]=YD.y; yv[11]=YD.z; yv[12]=YD.w; yv[13]=YE;
            } else if (rok) {
                const int gc = tx0 + c0;
                const float* prx = xp + (size_t)gy*W_IMG + gc;
                const float* pry = yp + (size_t)gy*W_IMG + gc;
#pragma unroll
                for (int j = 0; j < 14; ++j) {
                    bool ok = (unsigned)(gc + j) < (unsigned)W_IMG;
                    xv[j] = ok ? prx[j] : 0.f;
                    yv[j] = ok ? pry[j] : 0.f;
                }
            } else {
#pragma unroll
                for (int j = 0; j < 14; ++j) { xv[j] = 0.f; yv[j] = 0.f; }
            }

            // fused MSE: interior pixels are window j=5..8, rows 5..36
            if (rok && r >= HALO && r < HALO+TH) {
#pragma unroll
                for (int j = 5; j < 9; ++j) {
                    float d = xv[j] - yv[j];
                    mse_acc = fmaf(d, d, mse_acc);
                }
            }

            // Packed hconv: accumulator pairs (k,k+1) in f2; weights are
            // compile-time pairs -> v_pk_fma_f32.
            f2 A[5][2];
#pragma unroll
            for (int f = 0; f < 5; ++f) { A[f][0] = splat2(0.f); A[f][1] = splat2(0.f); }
#pragma unroll
            for (int j = 0; j < 14; ++j) {
                float px = xv[j], py = yv[j];
                float pxx = px*px, pyy = py*py, pxy = px*py;
#pragma unroll
                for (int p = 0; p < 2; ++p) {
                    const int t0 = j - 2*p;          // tap for k=2p; k=2p+1 uses t0-1
                    if (t0 >= 0 && t0 <= WS11) {     // at least one lane valid
                        const f2 wp = {WT(t0), WT(t0-1)};
                        A[0][p] = __builtin_elementwise_fma(wp, splat2(px),  A[0][p]);
                        A[1][p] = __builtin_elementwise_fma(wp, splat2(py),  A[1][p]);
                        A[2][p] = __builtin_elementwise_fma(wp, splat2(pxx), A[2][p]);
                        A[3][p] = __builtin_elementwise_fma(wp, splat2(pyy), A[3][p]);
                        A[4][p] = __builtin_elementwise_fma(wp, splat2(pxy), A[4][p]);
                    }
                }
            }
            float* wb = &rbuf[r*RS + c0];
#pragma unroll
            for (int f = 0; f < 5; ++f) {
                *(float4*)(wb + f*SH*RS) =
                    make_float4(A[f][0].x, A[f][0].y, A[f][1].x, A[f][1].y);
            }
        }
        __syncthreads();

        // ---- Stage B: vertical 11-tap conv + SSIM; 8 rows per thread,
        //      128 active threads; alternate wave-pairs across tiles. ----
        if (((tid >> 7) & 1) == (it & 1)) {
            const f2 c1 = {0.01f*0.01f, 0.01f*0.01f};
            const f2 c2 = {0.03f*0.03f, 0.03f*0.03f};
            const f2 two = {2.f, 2.f};
            const int s  = tid & 127;
            const int c  = s & 31;
            const int r0 = (s >> 5) << 3;    // 0, 8, 16, 24
            f2 acc2[5][4];
#pragma unroll
            for (int f = 0; f < 5; ++f)
#pragma unroll
                for (int p = 0; p < 4; ++p) acc2[f][p] = splat2(0.f);
#pragma unroll
            for (int f = 0; f < 5; ++f) {
                const float* rb = &rbuf[f*SH*RS + r0*RS + c];
#pragma unroll
                for (int i = 0; i < 18; ++i) {
                    float v = rb[i*RS];
#pragma unroll
                    for (int p = 0; p < 4; ++p) {
                        const int t0 = i - 2*p;
                        if (t0 >= 0 && t0 <= WS11) {
                            const f2 wp = {WT(t0), WT(t0-1)};
                            acc2[f][p] = __builtin_elementwise_fma(wp, splat2(v), acc2[f][p]);
                        }
                    }
                }
            }
#pragma unroll
            for (int p = 0; p < 4; ++p) {
                f2 mx = acc2[0][p], my = acc2[1][p];
                f2 sxx = acc2[2][p] - mx*mx;
                f2 syy = acc2[3][p] - my*my;
                f2 sxy = acc2[4][p] - mx*my;
                f2 num = (two*mx*my + c1) * (two*sxy + c2);
                f2 den = (mx*mx + my*my + c1) * (sxx + syy + c2);
                ssim_acc += __fdividef(num.x, den.x) + __fdividef(num.y, den.y);
            }
        }
        __syncthreads();   // rbuf reused by next tile
    }

    // ---- Block reduce (4 waves of 64) ----
#pragma unroll
    for (int off = 32; off > 0; off >>= 1) {
        ssim_acc += __shfl_down(ssim_acc, off);
        mse_acc  += __shfl_down(mse_acc, off);
    }
    int wid = tid >> 6, lane = tid & 63;
    if (lane == 0) { red[wid] = ssim_acc; red[4+wid] = mse_acc; }
    __syncthreads();
    if (tid == 0) {
        float s = red[0]+red[1]+red[2]+red[3];
        float m = red[4]+red[5]+red[6]+red[7];
        part[blockIdx.x] = s;
        part[nParts + blockIdx.x] = m;
    }
}

// 1024-thread finalize: vectorized partial reduce (double), fast-log BCE,
// curriculum weights.
#define FT 1024
__global__ __launch_bounds__(FT) void finalize_k(
        const float* __restrict__ part, int nParts,
        const float* __restrict__ wm_orig, const float* __restrict__ wm_ext,
        int nWm, const int* __restrict__ epoch_p,
        float* __restrict__ out, double inv_npix, double inv_nwm) {
    __shared__ double red[48];
    int tid = threadIdx.x;
    double s_ssim = 0.0, s_mse = 0.0, s_wl = 0.0;
    const float4* s4 = (const float4*)part;
    const float4* m4 = (const float4*)(part + nParts);
    int n4 = nParts >> 2;
    for (int i = tid; i < n4; i += FT) {
        float4 v = s4[i];
        s_ssim += (double)((v.x + v.y) + (v.z + v.w));
        float4 u = m4[i];
        s_mse  += (double)((u.x + u.y) + (u.z + u.w));
    }
    const float4* p4 = (const float4*)wm_orig;
    const float4* q4 = (const float4*)wm_ext;
    int w4 = nWm >> 2;
    for (int i = tid; i < w4; i += FT) {
        float4 p = p4[i], q = q4[i];
        float a;
        a  = -(p.x*__logf(q.x) + (1.f-p.x)*__logf(1.f-q.x));
        a += -(p.y*__logf(q.y) + (1.f-p.y)*__logf(1.f-q.y));
        a += -(p.z*__logf(q.z) + (1.f-p.z)*__logf(1.f-q.z));
        a += -(p.w*__logf(q.w) + (1.f-p.w)*__logf(1.f-q.w));
        s_wl += (double)a;
    }
#pragma unroll
    for (int off = 32; off > 0; off >>= 1) {
        s_ssim += __shfl_down(s_ssim, off);
        s_mse  += __shfl_down(s_mse, off);
        s_wl   += __shfl_down(s_wl, off);
    }
    int wid = tid >> 6, lane = tid & 63;
    if (lane == 0) { red[wid] = s_ssim; red[16+wid] = s_mse; red[32+wid] = s_wl; }
    __syncthreads();
    if (tid == 0) {
        double ssim_sum = 0.0, mse_sum = 0.0, wl_sum = 0.0;
        for (int i = 0; i < 16; ++i) {
            ssim_sum += red[i]; mse_sum += red[16+i]; wl_sum += red[32+i];
        }
        float sv = (float)(ssim_sum * inv_npix);
        float ml = (float)(mse_sum  * inv_npix);
        float wl = (float)(wl_sum   * inv_nwm);
        int e = *epoch_p;
        float w_img, w_ssim;
        if (e <= 12) {
            w_img = 0.05f; w_ssim = 0.05f;
        } else {
            float progress = fminf(1.0f, (float)(e - 12) / 10.0f);
            w_img  = 0.05f + (0.5f - 0.05f)*progress;
            w_ssim = 0.05f + (0.8f - 0.05f)*progress;
        }
        float sl = 1.0f - sv;
        float total = w_img*ml + w_ssim*sl + 3.0f*wl;
        out[0] = total;
        out[1] = ml;
        out[2] = sv;
        out[3] = wl;
    }
}

extern "C" void kernel_launch(void* const* d_in, const int* in_sizes, int n_in,
                              void* d_out, int out_size, void* d_ws, size_t ws_size,
                              hipStream_t stream) {
    const float* cover   = (const float*)d_in[0];
    const float* wmed    = (const float*)d_in[1];
    const float* wm_orig = (const float*)d_in[2];
    const float* wm_ext  = (const float*)d_in[3];
    const int*   epoch   = (const int*)d_in[4];
    float* out = (float*)d_out;

    int npix   = in_sizes[0];                 // 12,582,912
    int planes = npix / (H_IMG * W_IMG);      // 48
    int nWm    = in_sizes[2];                 // 16,384

    int nTiles  = 16 * 16 * planes;           // 12288
    int nBlocks = nTiles / TPB;               // 3072 blocks, 4 x-adjacent tiles
    int nParts  = nBlocks;
    float* part = (float*)d_ws;               // 2 * nParts floats (24 KB)

    ssim_mse_tile<<<nBlocks, NTHREADS, 0, stream>>>(cover, wmed, part, nParts);
    finalize_k<<<1, FT, 0, stream>>>(part, nParts, wm_orig, wm_ext, nWm,
                                     epoch, out,
                                     1.0 / (double)npix, 1.0 / (double)nWm);
}